// Round 5
// baseline (297.312 us; speedup 1.0000x reference)
//
#include <hip/hip_runtime.h>
#include <math.h>

// Problem constants (match reference setup_inputs)
constexpr int Bn = 131072;   // batch
constexpr int Fn = 1024;     // features (= GEMM K)
constexpr int Tn = 100;      // trees
constexpr int Kn = 32;       // features per tree

constexpr int TP = 112;            // trees padded to 7*16 (GEMM N)
constexpr int NF = TP / 16;        // 7 B-fragments
constexpr int BK = 64;             // floats per row per tile
constexpr int KS = BK / 32;        // 2 MFMA k-steps per tile
constexpr int NT = Fn / BK;        // 16 tiles
constexpr int BM = 128;            // rows per block
constexpr int MW = 32;             // rows per wave (wave-private)
constexpr int BLOCK = 256;
constexpr int GRID = Bn / BM;      // 1024 blocks

typedef __attribute__((ext_vector_type(8))) short bf16x8;
typedef __attribute__((ext_vector_type(4))) float f32x4;

// fp32 -> bf16 round-to-nearest-even
__device__ inline unsigned short f2bf(float f) {
    uint32_t u = __float_as_uint(f);
    return (unsigned short)((u + 0x7FFFu + ((u >> 16) & 1u)) >> 16);
}

// ---------------------------------------------------------------------------
// Prep: dense W_T bf16 [TP][Fn] + bias[TP] in workspace (unchanged, validated)
// ---------------------------------------------------------------------------
__global__ __launch_bounds__(64)
void rf_prep(const int* __restrict__ fidx, const float* __restrict__ fthr,
             const float* __restrict__ fw,
             unsigned short* __restrict__ wt, float* __restrict__ bias)
{
    const int t    = blockIdx.x;     // 0..111
    const int lane = threadIdx.x;    // 0..63

    int4 z = make_int4(0, 0, 0, 0);
    int4* rowp = (int4*)(wt + (size_t)t * Fn);
    rowp[lane * 2 + 0] = z;
    rowp[lane * 2 + 1] = z;
    __syncthreads();

    float bsum = 0.f;
    if (t < Tn && lane < Kn) {
        const int   idx = fidx[t * Kn + lane];
        const float w   = fw[t * Kn + lane];
        const float th  = fthr[t * Kn + lane];
        wt[(size_t)t * Fn + idx] = f2bf(w);
        bsum = th * w;
    }
#pragma unroll
    for (int d = 1; d < 64; d <<= 1) bsum += __shfl_xor(bsum, d, 64);
    if (lane == 0) bias[t] = (t < Tn) ? bsum : 0.f;
}

// ---------------------------------------------------------------------------
// Reg-staged barrier-free GEMM (T14): global_load_dwordx4 -> regs (2 tiles
// ahead) -> counted vmcnt -> ds_write_b128 (XOR-swizzled) -> ds_read -> MFMA.
// No global_load_lds anywhere (H5 test). Per-wave private LDS slices, no
// __syncthreads. Per-phase order: loadB(t) | issueA(t+2) | vmcnt(22) |
// writeA(t+1) | compute(t).  Compiler's B-wait then drains only to vmcnt(8),
// leaving the A(t+2) prefetch in flight.
// ---------------------------------------------------------------------------
__global__ __launch_bounds__(BLOCK, 2)
void rf_gemm(const float* __restrict__ x,
             const unsigned short* __restrict__ wt,
             const float* __restrict__ bias,
             float* __restrict__ out)
{
    __shared__ float lds[2][BM * BK];   // 2 x 32 KB

    const int lane = threadIdx.x & 63;
    const int wid  = threadIdx.x >> 6;
    const int rb   = blockIdx.x * BM;
    const int tofs = blockIdx.x & (NT - 1);   // per-block K-tile stagger

    // staging geometry: instr i covers rows i*4 + (lane>>4), chunk lane&15
    const int s_sub = lane >> 4;        // row within quad
    const int s_c   = lane & 15;        // logical 16B chunk (linear source!)
    // A-read geometry
    const int a_L = lane & 15;
    const int a_g = lane >> 4;

    // ds_write byte addresses (buf 0); phys chunk = logical ^ (row & 15)
    int waddr[8];
#pragma unroll
    for (int i = 0; i < 8; ++i) {
        const int row  = i * 4 + s_sub;
        const int phys = s_c ^ (row & 15);
        waddr[i] = wid * (MW * BK * 4) + row * (BK * 4) + phys * 16;
    }

    f32x4 acc[2][NF];
#pragma unroll
    for (int m = 0; m < 2; ++m)
#pragma unroll
        for (int f = 0; f < NF; ++f) acc[m][f] = (f32x4){0.f, 0.f, 0.f, 0.f};

    auto tileof = [&](int t) { return (t + tofs) & (NT - 1); };

    // 8 x global_load_dwordx4: 4 rows x 256B contiguous per instr, linear.
    auto issueA = [&](int t, float4 (&R)[8]) {
        const float* base = x + (size_t)(rb + wid * MW) * Fn + tileof(t) * BK;
#pragma unroll
        for (int i = 0; i < 8; ++i)
            R[i] = *(const float4*)(base + (size_t)(i * 4 + s_sub) * Fn + s_c * 4);
    };

    // 8 x ds_write_b128, XOR-swizzled (2-way bank aliasing = free)
    auto writeA = [&](const float4 (&R)[8], int bsel) {
        char* lp = (char*)&lds[0][0] + bsel * (BM * BK * 4);
#pragma unroll
        for (int i = 0; i < 8; ++i)
            *(float4*)(lp + waddr[i]) = R[i];
    };

    // 14 x dwordx4 from L2-resident wt
    auto loadB = [&](int t, bf16x8 (&bfr)[KS][NF]) {
        const int tp = tileof(t);
#pragma unroll
        for (int ks = 0; ks < KS; ++ks)
#pragma unroll
            for (int f = 0; f < NF; ++f) {
                const unsigned short* bp =
                    wt + (size_t)(f * 16 + a_L) * Fn + tp * BK + ks * 32 + a_g * 8;
                bfr[ks][f] = *(const bf16x8*)bp;
            }
    };

    // swizzled ds_read + cvt + MFMA (per-ks to keep af small)
    auto compute = [&](int bsel, bf16x8 (&bfr)[KS][NF]) {
        const char* lp = (const char*)&lds[0][0] + bsel * (BM * BK * 4)
                       + wid * (MW * BK * 4);
#pragma unroll
        for (int ks = 0; ks < KS; ++ks) {
            bf16x8 af[2];
#pragma unroll
            for (int m = 0; m < 2; ++m) {
                const char* rp = lp + (m * 16 + a_L) * (BK * 4);
                const int c0 = ks * 8 + a_g * 2;
                float4 lo = *(const float4*)(rp + ((c0 ^ a_L) * 16));
                float4 hi = *(const float4*)(rp + (((c0 + 1) ^ a_L) * 16));
                bf16x8 v;
                v[0] = (short)f2bf(lo.x); v[1] = (short)f2bf(lo.y);
                v[2] = (short)f2bf(lo.z); v[3] = (short)f2bf(lo.w);
                v[4] = (short)f2bf(hi.x); v[5] = (short)f2bf(hi.y);
                v[6] = (short)f2bf(hi.z); v[7] = (short)f2bf(hi.w);
                af[m] = v;
            }
#pragma unroll
            for (int m = 0; m < 2; ++m)
#pragma unroll
                for (int f = 0; f < NF; ++f)
                    acc[m][f] = __builtin_amdgcn_mfma_f32_16x16x32_bf16(
                        af[m], bfr[ks][f], acc[m][f], 0, 0, 0);
        }
    };

    float4 Ra[8], Rb[8];
    bf16x8 breg[KS][NF];

    // Prologue: A(0) -> buf0 (one-time vmcnt(0) via reg dep), A(1) in flight.
    issueA(0, Ra);
    writeA(Ra, 0);
    issueA(1, Ra);

    for (int t = 0; t < NT; t += 2) {
        // ---- even phase: consume tile t from buf[t&1] ----
        loadB(t, breg);                                      // [A(t+1):8, B(t):14]
        if (t + 2 < NT) {
            issueA(t + 2, Rb);                               // +8 -> 30
            asm volatile("s_waitcnt vmcnt(22)" ::: "memory");// drain A(t+1)
        } else {
            asm volatile("s_waitcnt vmcnt(14)" ::: "memory");// tail drain A(t+1)
        }
        writeA(Ra, (t + 1) & 1);                             // stage tile t+1
        compute(t & 1, breg);                                // B-wait -> vmcnt(8)

        // ---- odd phase: consume tile t+1 from buf[(t+1)&1] ----
        loadB(t + 1, breg);
        if (t + 3 < NT) {
            issueA(t + 3, Ra);
            asm volatile("s_waitcnt vmcnt(22)" ::: "memory");// drain A(t+2)
        } else if (t + 2 < NT) {
            asm volatile("s_waitcnt vmcnt(14)" ::: "memory");// drain A(t+2)
        }
        if (t + 2 < NT) writeA(Rb, (t + 2) & 1);             // stage tile t+2
        compute((t + 1) & 1, breg);
    }

    // ---- epilogue: ws = acc - bias; p = sigmoid; mean over trees ----
    const int col = lane & 15;     // C col = lane&15, row = (lane>>4)*4 + reg
    float psum[2][4] = {};
#pragma unroll
    for (int f = 0; f < NF; ++f) {
        const int  n     = f * 16 + col;
        const bool valid = n < Tn;
        const float bv   = bias[n];   // zero-padded
#pragma unroll
        for (int m = 0; m < 2; ++m)
#pragma unroll
            for (int r = 0; r < 4; ++r) {
                const float ws = acc[m][f][r] - bv;
                const float p  = 1.f / (1.f + __expf(-ws));
                if (valid) psum[m][r] += p;
            }
    }
#pragma unroll
    for (int m = 0; m < 2; ++m)
#pragma unroll
        for (int r = 0; r < 4; ++r)
#pragma unroll
            for (int d = 1; d < 16; d <<= 1)
                psum[m][r] += __shfl_xor(psum[m][r], d, 64);

    const int g = lane >> 4;
#pragma unroll
    for (int m = 0; m < 2; ++m) {
        if (col < 4) {
            const int r   = col;
            const int row = rb + wid * MW + m * 16 + g * 4 + r;
            const float pm = psum[m][r] * (1.0f / Tn);
            *(float2*)(out + (size_t)row * 2) = make_float2(1.0f - pm, pm);
        }
    }
}

extern "C" void kernel_launch(void* const* d_in, const int* in_sizes, int n_in,
                              void* d_out, int out_size, void* d_ws, size_t ws_size,
                              hipStream_t stream) {
    const float* x    = (const float*)d_in[0];
    const int*   fidx = (const int*)  d_in[1];
    const float* fthr = (const float*)d_in[2];
    const float* fw   = (const float*)d_in[3];
    float*       out  = (float*)d_out;

    unsigned short* wt   = (unsigned short*)d_ws;                       // 229376 B
    float*          bias = (float*)((char*)d_ws + (size_t)TP * Fn * 2); // +448 B

    rf_prep<<<TP, 64, 0, stream>>>(fidx, fthr, fw, wt, bias);
    rf_gemm<<<GRID, BLOCK, 0, stream>>>(x, wt, bias, out);
}

// Round 6
// 264.016 us; speedup vs baseline: 1.1261x; 1.1261x over previous
//
#include <hip/hip_runtime.h>
#include <math.h>

// Problem constants (match reference setup_inputs)
constexpr int Bn = 131072;   // batch
constexpr int Fn = 1024;     // features (= GEMM K)
constexpr int Tn = 100;      // trees
constexpr int Kn = 32;       // features per tree

constexpr int TP  = 112;           // trees padded to 7*16 (GEMM N)
constexpr int NF  = TP / 16;       // 7 B-fragments
constexpr int NKS = Fn / 32;       // 32 MFMA k-steps
constexpr int BM  = 128;           // rows per block
constexpr int MW  = 32;            // rows per wave (2 A-fragments)
constexpr int BLOCK = 256;
constexpr int GRID  = Bn / BM;     // 1024 blocks

typedef __attribute__((ext_vector_type(8))) short bf16x8;
typedef __attribute__((ext_vector_type(4))) float f32x4;

// fp32 -> bf16 round-to-nearest-even
__device__ inline unsigned short f2bf(float f) {
    uint32_t u = __float_as_uint(f);
    return (unsigned short)((u + 0x7FFFu + ((u >> 16) & 1u)) >> 16);
}

__device__ inline bf16x8 cvt8(float4 lo, float4 hi) {
    bf16x8 v;
    v[0] = (short)f2bf(lo.x); v[1] = (short)f2bf(lo.y);
    v[2] = (short)f2bf(lo.z); v[3] = (short)f2bf(lo.w);
    v[4] = (short)f2bf(hi.x); v[5] = (short)f2bf(hi.y);
    v[6] = (short)f2bf(hi.z); v[7] = (short)f2bf(hi.w);
    return v;
}

// ---------------------------------------------------------------------------
// Prep: dense W_T bf16 [TP][Fn] + bias[TP] in workspace (unchanged, validated)
// ---------------------------------------------------------------------------
__global__ __launch_bounds__(64)
void rf_prep(const int* __restrict__ fidx, const float* __restrict__ fthr,
             const float* __restrict__ fw,
             unsigned short* __restrict__ wt, float* __restrict__ bias)
{
    const int t    = blockIdx.x;     // 0..111
    const int lane = threadIdx.x;    // 0..63

    int4 z = make_int4(0, 0, 0, 0);
    int4* rowp = (int4*)(wt + (size_t)t * Fn);
    rowp[lane * 2 + 0] = z;
    rowp[lane * 2 + 1] = z;
    __syncthreads();

    float bsum = 0.f;
    if (t < Tn && lane < Kn) {
        const int   idx = fidx[t * Kn + lane];
        const float w   = fw[t * Kn + lane];
        const float th  = fthr[t * Kn + lane];
        wt[(size_t)t * Fn + idx] = f2bf(w);
        bsum = th * w;
    }
#pragma unroll
    for (int d = 1; d < 64; d <<= 1) bsum += __shfl_xor(bsum, d, 64);
    if (lane == 0) bias[t] = (t < Tn) ? bsum : 0.f;
}

// ---------------------------------------------------------------------------
// Zero-LDS GEMM: A loaded global->VGPR directly in MFMA fragment layout.
// lane(g=lane>>4, r=lane&15): A row r of the 16-row frag, bytes [g*32,+32)
// of each 128-B k-window = 2 dwordx4, 100% line utilization (4 g-lanes of a
// row cover one line exactly). One k-step prefetch, counted vmcnt(11).
// No arrays in the hot path (round-5 scratch lesson): named regs only.
// ---------------------------------------------------------------------------
#define ISSUE(ks, A0, A1, A2, A3, B0, B1, B2, B3, B4, B5, B6) do {        \
    A0 = *(const float4*)(pa0 + (ks) * 32);                               \
    A1 = *(const float4*)(pa0 + (ks) * 32 + 4);                          \
    A2 = *(const float4*)(pa1 + (ks) * 32);                              \
    A3 = *(const float4*)(pa1 + (ks) * 32 + 4);                          \
    B0 = *(const bf16x8*)(pb0 + (ks) * 32);                              \
    B1 = *(const bf16x8*)(pb1 + (ks) * 32);                              \
    B2 = *(const bf16x8*)(pb2 + (ks) * 32);                              \
    B3 = *(const bf16x8*)(pb3 + (ks) * 32);                              \
    B4 = *(const bf16x8*)(pb4 + (ks) * 32);                              \
    B5 = *(const bf16x8*)(pb5 + (ks) * 32);                              \
    B6 = *(const bf16x8*)(pb6 + (ks) * 32);                              \
} while (0)

#define STEP(A0, A1, A2, A3, B0, B1, B2, B3, B4, B5, B6) do {             \
    bf16x8 fa0 = cvt8(A0, A1);                                            \
    bf16x8 fa1 = cvt8(A2, A3);                                            \
    acc00 = __builtin_amdgcn_mfma_f32_16x16x32_bf16(fa0, B0, acc00,0,0,0);\
    acc01 = __builtin_amdgcn_mfma_f32_16x16x32_bf16(fa0, B1, acc01,0,0,0);\
    acc02 = __builtin_amdgcn_mfma_f32_16x16x32_bf16(fa0, B2, acc02,0,0,0);\
    acc03 = __builtin_amdgcn_mfma_f32_16x16x32_bf16(fa0, B3, acc03,0,0,0);\
    acc04 = __builtin_amdgcn_mfma_f32_16x16x32_bf16(fa0, B4, acc04,0,0,0);\
    acc05 = __builtin_amdgcn_mfma_f32_16x16x32_bf16(fa0, B5, acc05,0,0,0);\
    acc06 = __builtin_amdgcn_mfma_f32_16x16x32_bf16(fa0, B6, acc06,0,0,0);\
    acc10 = __builtin_amdgcn_mfma_f32_16x16x32_bf16(fa1, B0, acc10,0,0,0);\
    acc11 = __builtin_amdgcn_mfma_f32_16x16x32_bf16(fa1, B1, acc11,0,0,0);\
    acc12 = __builtin_amdgcn_mfma_f32_16x16x32_bf16(fa1, B2, acc12,0,0,0);\
    acc13 = __builtin_amdgcn_mfma_f32_16x16x32_bf16(fa1, B3, acc13,0,0,0);\
    acc14 = __builtin_amdgcn_mfma_f32_16x16x32_bf16(fa1, B4, acc14,0,0,0);\
    acc15 = __builtin_amdgcn_mfma_f32_16x16x32_bf16(fa1, B5, acc15,0,0,0);\
    acc16 = __builtin_amdgcn_mfma_f32_16x16x32_bf16(fa1, B6, acc16,0,0,0);\
} while (0)

__global__ __launch_bounds__(BLOCK)
void rf_gemm(const float* __restrict__ x,
             const unsigned short* __restrict__ wt,
             const float* __restrict__ bias,
             float* __restrict__ out)
{
    const int lane = threadIdx.x & 63;
    const int wid  = threadIdx.x >> 6;
    const int rb   = blockIdx.x * BM;
    const int r    = lane & 15;
    const int g    = lane >> 4;

    // A base pointers: rows rb + wid*32 + {r, 16+r}, k-offset g*8
    const float* pa0 = x + (size_t)(rb + wid * MW + r) * Fn + g * 8;
    const float* pa1 = pa0 + (size_t)16 * Fn;
    // B base pointers per fragment
    const unsigned short* pb0 = wt + (size_t)(0 * 16 + r) * Fn + g * 8;
    const unsigned short* pb1 = wt + (size_t)(1 * 16 + r) * Fn + g * 8;
    const unsigned short* pb2 = wt + (size_t)(2 * 16 + r) * Fn + g * 8;
    const unsigned short* pb3 = wt + (size_t)(3 * 16 + r) * Fn + g * 8;
    const unsigned short* pb4 = wt + (size_t)(4 * 16 + r) * Fn + g * 8;
    const unsigned short* pb5 = wt + (size_t)(5 * 16 + r) * Fn + g * 8;
    const unsigned short* pb6 = wt + (size_t)(6 * 16 + r) * Fn + g * 8;

    f32x4 acc00 = {0,0,0,0}, acc01 = {0,0,0,0}, acc02 = {0,0,0,0},
          acc03 = {0,0,0,0}, acc04 = {0,0,0,0}, acc05 = {0,0,0,0},
          acc06 = {0,0,0,0};
    f32x4 acc10 = {0,0,0,0}, acc11 = {0,0,0,0}, acc12 = {0,0,0,0},
          acc13 = {0,0,0,0}, acc14 = {0,0,0,0}, acc15 = {0,0,0,0},
          acc16 = {0,0,0,0};

    float4 cA0, cA1, cA2, cA3, nA0, nA1, nA2, nA3;
    bf16x8 cB0, cB1, cB2, cB3, cB4, cB5, cB6;
    bf16x8 nB0, nB1, nB2, nB3, nB4, nB5, nB6;

    ISSUE(0, cA0, cA1, cA2, cA3, cB0, cB1, cB2, cB3, cB4, cB5, cB6);

#pragma unroll
    for (int ks = 0; ks < NKS; ks += 2) {
        // ks+1 <= 31 always valid
        ISSUE(ks + 1, nA0, nA1, nA2, nA3, nB0, nB1, nB2, nB3, nB4, nB5, nB6);
        asm volatile("s_waitcnt vmcnt(11)" ::: "memory");   // c-set landed
        STEP(cA0, cA1, cA2, cA3, cB0, cB1, cB2, cB3, cB4, cB5, cB6);

        if (ks + 2 < NKS) {
            ISSUE(ks + 2, cA0, cA1, cA2, cA3, cB0, cB1, cB2, cB3, cB4, cB5, cB6);
            asm volatile("s_waitcnt vmcnt(11)" ::: "memory");   // n-set landed
        } else {
            asm volatile("s_waitcnt vmcnt(0)" ::: "memory");    // tail drain
        }
        STEP(nA0, nA1, nA2, nA3, nB0, nB1, nB2, nB3, nB4, nB5, nB6);
    }

    // ---- epilogue: ws = acc - bias; p = sigmoid; mean over trees ----
    f32x4 accA[2][NF] = {
        { acc00, acc01, acc02, acc03, acc04, acc05, acc06 },
        { acc10, acc11, acc12, acc13, acc14, acc15, acc16 }
    };

    const int col = lane & 15;     // C col = lane&15, row = (lane>>4)*4 + reg
    float psum[2][4] = {};
#pragma unroll
    for (int f = 0; f < NF; ++f) {
        const int  n     = f * 16 + col;
        const bool valid = n < Tn;
        const float bv   = bias[n];   // zero-padded
#pragma unroll
        for (int m = 0; m < 2; ++m)
#pragma unroll
            for (int q = 0; q < 4; ++q) {
                const float ws = accA[m][f][q] - bv;
                const float p  = 1.f / (1.f + __expf(-ws));
                if (valid) psum[m][q] += p;
            }
    }
#pragma unroll
    for (int m = 0; m < 2; ++m)
#pragma unroll
        for (int q = 0; q < 4; ++q)
#pragma unroll
            for (int d = 1; d < 16; d <<= 1)
                psum[m][q] += __shfl_xor(psum[m][q], d, 64);

#pragma unroll
    for (int m = 0; m < 2; ++m) {
        if (col < 4) {   // lane col==q writes row g*4 + q of this fragment
            const int q   = col;
            const int row = rb + wid * MW + m * 16 + g * 4 + q;
            const float pm = psum[m][q] * (1.0f / Tn);
            *(float2*)(out + (size_t)row * 2) = make_float2(1.0f - pm, pm);
        }
    }
}

extern "C" void kernel_launch(void* const* d_in, const int* in_sizes, int n_in,
                              void* d_out, int out_size, void* d_ws, size_t ws_size,
                              hipStream_t stream) {
    const float* x    = (const float*)d_in[0];
    const int*   fidx = (const int*)  d_in[1];
    const float* fthr = (const float*)d_in[2];
    const float* fw   = (const float*)d_in[3];
    float*       out  = (float*)d_out;

    unsigned short* wt   = (unsigned short*)d_ws;                       // 229376 B
    float*          bias = (float*)((char*)d_ws + (size_t)TP * Fn * 2); // +448 B

    rf_prep<<<TP, 64, 0, stream>>>(fidx, fthr, fw, wt, bias);
    rf_gemm<<<GRID, BLOCK, 0, stream>>>(x, wt, bias, out);
}

// Round 7
// 139.358 us; speedup vs baseline: 2.1334x; 1.8945x over previous
//
#include <hip/hip_runtime.h>
#include <math.h>

// Problem constants (match reference setup_inputs)
constexpr int Bn = 131072;   // batch
constexpr int Fn = 1024;     // features
constexpr int Tn = 100;      // trees
constexpr int Kn = 32;       // features per tree

constexpr int BLOCK = 256;
constexpr int WPB   = BLOCK / 64;   // 4 waves/block
constexpr int GRID  = 1024;         // 4 blocks/CU
constexpr int NW    = GRID * WPB;   // 4096 waves
constexpr int RPW   = Bn / NW;      // 32 rows per wave, exact

typedef __attribute__((ext_vector_type(4))) float f32x4;

// Load one 4KB row into 4 named f32x4 regs (nt: bypass cache allocation)
#define NTLD(D0, D1, D2, D3, PTR) do {                       \
    const f32x4* _s = (const f32x4*)(PTR);                   \
    D0 = __builtin_nontemporal_load(_s + lane);              \
    D1 = __builtin_nontemporal_load(_s + 64 + lane);         \
    D2 = __builtin_nontemporal_load(_s + 128 + lane);        \
    D3 = __builtin_nontemporal_load(_s + 192 + lane);        \
} while (0)

// Write the 4 regs to this wave's LDS row buffer (4 x ds_write_b128, linear)
#define DSWR(BUFP, R0, R1, R2, R3) do {                      \
    f32x4* _d = (f32x4*)(BUFP);                              \
    _d[lane]       = R0;                                     \
    _d[64 + lane]  = R1;                                     \
    _d[128 + lane] = R2;                                     \
    _d[192 + lane] = R3;                                     \
} while (0)

// Gather-dot both trees, sigmoid, 64-lane reduce, lane0 stores float2
#define GATHER_COMPUTE(BUFP, ROW) do {                                     \
    const char* _cb = (const char*)(BUFP);                                 \
    float _a0 = 0.f, _a1 = 0.f;                                            \
    _Pragma("unroll")                                                      \
    for (int _k = 0; _k < Kn; ++_k) {                                      \
        const uint32_t _u0 = pk0[_k];                                      \
        const uint32_t _u1 = pk1[_k];                                      \
        _a0 = fmaf(*(const float*)(_cb + (_u0 & 0xFFFu)),                  \
                   __uint_as_float(_u0 & 0xFFFFF000u), _a0);               \
        _a1 = fmaf(*(const float*)(_cb + (_u1 & 0xFFFu)),                  \
                   __uint_as_float(_u1 & 0xFFFFF000u), _a1);               \
    }                                                                      \
    const float _p0 = 1.f / (1.f + __expf(-(_a0 - bias0)));                \
    const float _p1 = 1.f / (1.f + __expf(-(_a1 - bias1)));                \
    float _s = _p0 + (has1 ? _p1 : 0.f);                                   \
    _Pragma("unroll")                                                      \
    for (int _d = 1; _d < 64; _d <<= 1) _s += __shfl_xor(_s, _d, 64);      \
    if (lane == 0) {                                                       \
        const float _pm = _s * (1.0f / Tn);                                \
        *(float2*)(out + (size_t)(ROW) * 2) = make_float2(1.0f - _pm, _pm);\
    }                                                                      \
} while (0)

__global__ __launch_bounds__(BLOCK)
void rf_fwd(const float* __restrict__ x,
            const int*   __restrict__ fidx,
            const float* __restrict__ fthr,
            const float* __restrict__ fw,
            float*       __restrict__ out)
{
    __shared__ float ldsbuf[WPB][2][Fn];   // 32 KB/block

    const int lane  = threadIdx.x & 63;
    const int wid   = threadIdx.x >> 6;
    const int gwave = blockIdx.x * WPB + wid;   // 0..4095

    // Lane handles tree t0 = lane, and t1 = 64+lane when it exists.
    const int  t0   = lane;
    const bool has1 = (64 + lane) < Tn;
    const int  t1   = has1 ? (64 + lane) : lane;

    // ---- Packed per-lane tables: u32 = (w & 0xFFFFF000) | (idx*4) ----
    // w truncated to 11 mantissa bits (rel err <= 2.4e-4); idx*4 = byte offset.
    uint32_t pk0[Kn], pk1[Kn];
    float bias0 = 0.f, bias1 = 0.f;

#pragma unroll
    for (int k = 0; k < Kn; k += 4) {
        int4   i4 = *(const int4*)  (fidx + t0 * Kn + k);
        float4 wv = *(const float4*)(fw   + t0 * Kn + k);
        float4 th = *(const float4*)(fthr + t0 * Kn + k);
        uint32_t wb0 = __float_as_uint(wv.x) & 0xFFFFF000u;
        uint32_t wb1 = __float_as_uint(wv.y) & 0xFFFFF000u;
        uint32_t wb2 = __float_as_uint(wv.z) & 0xFFFFF000u;
        uint32_t wb3 = __float_as_uint(wv.w) & 0xFFFFF000u;
        pk0[k+0] = wb0 | ((uint32_t)i4.x << 2);
        pk0[k+1] = wb1 | ((uint32_t)i4.y << 2);
        pk0[k+2] = wb2 | ((uint32_t)i4.z << 2);
        pk0[k+3] = wb3 | ((uint32_t)i4.w << 2);
        bias0 += th.x*__uint_as_float(wb0) + th.y*__uint_as_float(wb1)
               + th.z*__uint_as_float(wb2) + th.w*__uint_as_float(wb3);
    }
#pragma unroll
    for (int k = 0; k < Kn; k += 4) {
        int4   i4 = *(const int4*)  (fidx + t1 * Kn + k);
        float4 wv = *(const float4*)(fw   + t1 * Kn + k);
        float4 th = *(const float4*)(fthr + t1 * Kn + k);
        uint32_t wb0 = __float_as_uint(wv.x) & 0xFFFFF000u;
        uint32_t wb1 = __float_as_uint(wv.y) & 0xFFFFF000u;
        uint32_t wb2 = __float_as_uint(wv.z) & 0xFFFFF000u;
        uint32_t wb3 = __float_as_uint(wv.w) & 0xFFFFF000u;
        pk1[k+0] = wb0 | ((uint32_t)i4.x << 2);
        pk1[k+1] = wb1 | ((uint32_t)i4.y << 2);
        pk1[k+2] = wb2 | ((uint32_t)i4.z << 2);
        pk1[k+3] = wb3 | ((uint32_t)i4.w << 2);
        bias1 += th.x*__uint_as_float(wb0) + th.y*__uint_as_float(wb1)
               + th.z*__uint_as_float(wb2) + th.w*__uint_as_float(wb3);
    }

    float* buf0 = &ldsbuf[wid][0][0];
    float* buf1 = &ldsbuf[wid][1][0];

    // Wave's rows: gwave + i*NW, i = 0..RPW-1 (exact, no guards needed)
    const float*  row0   = x + (size_t)gwave * Fn;
    const size_t  rstr   = (size_t)NW * Fn;

    f32x4 A0, A1, A2, A3, B0, B1, B2, B3;

    // Prologue: rows i=0 (A) and i=1 (B) in flight
    NTLD(A0, A1, A2, A3, row0);
    NTLD(B0, B1, B2, B3, row0 + rstr);

    for (int i = 0; i < RPW; i += 2) {
        // ---- even: row i (A-set) -> buf0 ----
        DSWR(buf0, A0, A1, A2, A3);            // compiler waits vmcnt for A here
        if (i + 2 < RPW)
            NTLD(A0, A1, A2, A3, row0 + (size_t)(i + 2) * rstr);
        GATHER_COMPUTE(buf0, gwave + (size_t)i * NW);   // lgkm-ordered by compiler

        // ---- odd: row i+1 (B-set) -> buf1 ----
        DSWR(buf1, B0, B1, B2, B3);
        if (i + 3 < RPW)
            NTLD(B0, B1, B2, B3, row0 + (size_t)(i + 3) * rstr);
        GATHER_COMPUTE(buf1, gwave + (size_t)(i + 1) * NW);
    }
}

extern "C" void kernel_launch(void* const* d_in, const int* in_sizes, int n_in,
                              void* d_out, int out_size, void* d_ws, size_t ws_size,
                              hipStream_t stream) {
    const float* x    = (const float*)d_in[0];
    const int*   fidx = (const int*)  d_in[1];
    const float* fthr = (const float*)d_in[2];
    const float* fw   = (const float*)d_in[3];
    float*       out  = (float*)d_out;

    rf_fwd<<<GRID, BLOCK, 0, stream>>>(x, fidx, fthr, fw, out);
}